// Round 8
// baseline (133.517 us; speedup 1.0000x reference)
//
#include <hip/hip_runtime.h>

typedef __bf16 bf16x8 __attribute__((ext_vector_type(8)));
typedef float f32x4 __attribute__((ext_vector_type(4)));
typedef float f32x16 __attribute__((ext_vector_type(16)));
typedef unsigned short u16;
typedef u16 u16x8 __attribute__((ext_vector_type(8)));
typedef unsigned int u32;
typedef u32 u32x4 __attribute__((ext_vector_type(4)));

#define DEVFN static __device__ __forceinline__

DEVFN u16 f2bf(float x) {  // RNE float->bf16 (finite inputs)
  u32 u = __builtin_bit_cast(u32, x);
  u32 r = u + 0x7FFFu + ((u >> 16) & 1u);
  return (u16)(r >> 16);
}

DEVFN float myexp2(float x) {
#if __has_builtin(__builtin_amdgcn_exp2f)
  return __builtin_amdgcn_exp2f(x);
#else
  return exp2f(x);
#endif
}

DEVFN u32 cvt_pk_bf16(float lo, float hi) {  // RNE pack: lo->[15:0], hi->[31:16]
  u32 r;
  asm("v_cvt_pk_bf16_f32 %0, %1, %2" : "=v"(r) : "v"(lo), "v"(hi));
  return r;
}

// ---------------------------------------------------------------------------
// Projection: E[b,o,f] = sum_c W[o,c] X[b,c,f] + bias[o], cast to bf16.
// mat 0 (Q): transposed [b][n][f][h], scaled by ALPHA*log2(e); 1 (K): same
// layout unscaled; 2 (V): natural [b][o][t].
// ---------------------------------------------------------------------------
__global__ __launch_bounds__(256, 2) void proj_kernel(
    const float* __restrict__ from_t, const float* __restrict__ to_t,
    const float* __restrict__ Wq, const float* __restrict__ bq,
    const float* __restrict__ Wk, const float* __restrict__ bk,
    const float* __restrict__ Wv, const float* __restrict__ bv,
    u16* __restrict__ qt, u16* __restrict__ kt, u16* __restrict__ vt) {
  const int d     = blockIdx.x;         // 768
  const int xcd   = d & 7;
  const int b     = xcd >> 1;
  const int fh    = xcd & 1;
  const int local = d >> 3;             // 0..95
  const int mat   = local >> 5;         // 0..2
  const int o0    = ((local >> 3) & 3) * 128;
  const int f0    = (fh * 8 + (local & 7)) * 128;

  const float* X    = (mat == 0) ? from_t : to_t;
  const float* W    = (mat == 0) ? Wq : (mat == 1 ? Wk : Wv);
  const float* bias = (mat == 0) ? bq : (mat == 1 ? bk : bv);
  const bool isT = (mat < 2);

  __shared__ u16 Xs[128][64];  // Xs[f][c] = X[c][f], 16B-chunk xor-swizzled
  __shared__ u16 Ws[128][64];  // Ws[o][c] = W[o][c], swizzled

  const int tid  = threadIdx.x;
  const int lane = tid & 63;
  const int w    = tid >> 6;

  f32x4 acc[4][4];
#pragma unroll
  for (int i = 0; i < 4; ++i)
#pragma unroll
    for (int j = 0; j < 4; ++j)
#pragma unroll
      for (int r = 0; r < 4; ++r) acc[i][j][r] = 0.f;

  const int arow0 = (w & 1) * 64;
  const int brow0 = (w >> 1) * 64;

  for (int c0 = 0; c0 < 512; c0 += 64) {
    __syncthreads();
#pragma unroll
    for (int i = 0; i < 4; ++i) {
      const int task = tid + 256 * i;
      const int f = task & 127, cg = task >> 7;
      const float* xp = X + ((size_t)b * 512 + c0 + cg * 8) * 2048 + f0 + f;
      float xv[8];
#pragma unroll
      for (int j = 0; j < 8; ++j) xv[j] = xp[(size_t)j * 2048];
      u32x4 pk;
#pragma unroll
      for (int j = 0; j < 4; ++j) pk[j] = cvt_pk_bf16(xv[2 * j], xv[2 * j + 1]);
      *(u32x4*)&Xs[f][(cg ^ (f & 7)) * 8] = pk;
    }
#pragma unroll
    for (int i = 0; i < 4; ++i) {
      const int task = tid + 256 * i;
      const int o = task & 127, cg = task >> 7;
      const float* wp = W + (size_t)(o0 + o) * 512 + c0 + cg * 8;
      const float4 w0 = *(const float4*)(wp);
      const float4 w1 = *(const float4*)(wp + 4);
      u32x4 pk;
      pk[0] = cvt_pk_bf16(w0.x, w0.y);
      pk[1] = cvt_pk_bf16(w0.z, w0.w);
      pk[2] = cvt_pk_bf16(w1.x, w1.y);
      pk[3] = cvt_pk_bf16(w1.z, w1.w);
      *(u32x4*)&Ws[o][(cg ^ (o & 7)) * 8] = pk;
    }
    __syncthreads();

#pragma unroll
    for (int kk = 0; kk < 2; ++kk) {
      const int cb8 = kk * 4;
      bf16x8 afr[4], bfr[4];
#pragma unroll
      for (int mi = 0; mi < 4; ++mi) {
        const int row = arow0 + mi * 16 + (lane & 15);
        const int ch  = (cb8 + (lane >> 4)) ^ (row & 7);
        afr[mi] = *(const bf16x8*)&(isT ? Xs : Ws)[row][ch * 8];
      }
#pragma unroll
      for (int ni = 0; ni < 4; ++ni) {
        const int row = brow0 + ni * 16 + (lane & 15);
        const int ch  = (cb8 + (lane >> 4)) ^ (row & 7);
        bfr[ni] = *(const bf16x8*)&(isT ? Ws : Xs)[row][ch * 8];
      }
#pragma unroll
      for (int mi = 0; mi < 4; ++mi)
#pragma unroll
        for (int ni = 0; ni < 4; ++ni)
          acc[mi][ni] = __builtin_amdgcn_mfma_f32_16x16x32_bf16(
              afr[mi], bfr[ni], acc[mi][ni], 0, 0, 0);
    }
  }

  const float qscale = 0.18033688011112042f;  // (1/8) * log2(e)
#pragma unroll
  for (int mi = 0; mi < 4; ++mi)
#pragma unroll
    for (int ni = 0; ni < 4; ++ni)
#pragma unroll
      for (int r = 0; r < 4; ++r) {
        const int rA = arow0 + mi * 16 + (lane >> 4) * 4 + r;
        const int cB = brow0 + ni * 16 + (lane & 15);
        int f, o;
        if (isT) { f = f0 + rA; o = o0 + cB; }
        else     { o = o0 + rA; f = f0 + cB; }
        float val = acc[mi][ni][r] + bias[o];
        if (mat == 0) val *= qscale;
        const u16 hv = f2bf(val);
        if (isT) {
          u16* dst = (mat == 0) ? qt : kt;
          dst[(((size_t)b * 8 + (o >> 6)) * 2048 + f) * 64 + (o & 63)] = hv;
        } else {
          vt[((size_t)b * 512 + o) * 2048 + f] = hv;
        }
      }
}

// ---------------------------------------------------------------------------
// Attention: 1024 blocks x 128 thr (2 waves x 32 q-rows), KVBLK=64, LDS dbuf.
// Same one-round-deep pipeline as r7 (verified): round r reads V_r + K_{r+1}
// to regs, stage(r+2)/mask(r+1) prefetch, QK_{r+1} MFMA interleaves with
// softmax_r VALU -> PV_r. Smaller blocks -> 4 desynced sync-groups/CU,
// 2-wave barriers (convoy fix). Each wave stages 32 rows (8 gload_lds);
// vmcnt(8) retires the stage group (stages issue before mask loads).
// n varies slowest across local idx -> co-dispatched blocks share K/V.
// ---------------------------------------------------------------------------
#define SB __builtin_amdgcn_sched_barrier(0)

#define STAGE(BB, T0)                                                          \
  do {                                                                         \
    _Pragma("unroll")                                                          \
    for (int j_ = 0; j_ < 4; ++j_)                                             \
      __builtin_amdgcn_global_load_lds(                                        \
          (const __attribute__((address_space(1))) void*)(                     \
              ksrc + ((size_t)(T0) + j_ * 8) * 64),                            \
          (__attribute__((address_space(3))) void*)&Ks[BB][w * 32 + j_ * 8][0],\
          16, 0, 0);                                                           \
    _Pragma("unroll")                                                          \
    for (int j_ = 0; j_ < 4; ++j_)                                             \
      __builtin_amdgcn_global_load_lds(                                        \
          (const __attribute__((address_space(1))) void*)(                     \
              vsrc + (size_t)j_ * 8 * 2048 + (T0)),                            \
          (__attribute__((address_space(3))) void*)&Vs[BB][w * 32 + j_ * 8][0],\
          16, 0, 0);                                                           \
  } while (0)

#define MLOAD(MK, T0)                                                          \
  do {                                                                         \
    _Pragma("unroll")                                                          \
    for (int i_ = 0; i_ < 8; ++i_)                                             \
      MK[i_] = *(const float4*)(mrow + (T0) + (i_ >> 2) * 32 + (i_ & 3) * 8 + g * 4); \
  } while (0)

#define LDK(BUF)                                                               \
  do {                                                                         \
    _Pragma("unroll")                                                          \
    for (int kf_ = 0; kf_ < 4; ++kf_)                                          \
      _Pragma("unroll")                                                        \
      for (int mi_ = 0; mi_ < 2; ++mi_) {                                      \
        const int row_ = mi_ * 32 + fl;                                        \
        kreg[mi_][kf_] =                                                       \
            *(const bf16x8*)&Ks[BUF][row_][((kf_ * 2 + g) ^ (row_ & 7)) * 8];  \
      }                                                                        \
  } while (0)

#define LDV(BUF)                                                               \
  do {                                                                         \
    _Pragma("unroll")                                                          \
    for (int tf_ = 0; tf_ < 4; ++tf_)                                          \
      _Pragma("unroll")                                                        \
      for (int mh_ = 0; mh_ < 2; ++mh_) {                                      \
        const int row_ = mh_ * 32 + fl;                                        \
        vreg[mh_][tf_] =                                                       \
            *(const bf16x8*)&Vs[BUF][row_][((tf_ * 2 + g) ^ (row_ & 7)) * 8];  \
      }                                                                        \
  } while (0)

// QK into SN (C=0), from kreg
#define QKMM(SN)                                                               \
  do {                                                                         \
    _Pragma("unroll")                                                          \
    for (int m_ = 0; m_ < 2; ++m_)                                             \
      _Pragma("unroll")                                                        \
      for (int r_ = 0; r_ < 16; ++r_) SN[m_][r_] = 0.f;                        \
    __builtin_amdgcn_s_setprio(1);                                             \
    _Pragma("unroll")                                                          \
    for (int kf_ = 0; kf_ < 4; ++kf_)                                          \
      _Pragma("unroll")                                                        \
      for (int mi_ = 0; mi_ < 2; ++mi_)                                        \
        SN[mi_] = __builtin_amdgcn_mfma_f32_32x32x16_bf16(kreg[mi_][kf_],      \
                                                          qf[kf_], SN[mi_],    \
                                                          0, 0, 0);            \
    __builtin_amdgcn_s_setprio(0);                                             \
  } while (0)

// Round r: RB = r&1; SC/MKC current (consumed), SN/MKN next (produced); T0=r*64
#define ROUND(RB, SC, SN, MKC, MKN, T0)                                        \
  {                                                                            \
    asm volatile("s_waitcnt vmcnt(8)" ::: "memory");                           \
    SB;                                                                        \
    __builtin_amdgcn_s_barrier();                                              \
    SB;                                                                        \
    LDV(RB);                                                                   \
    LDK(RB ^ 1);                                                               \
    asm volatile("s_waitcnt lgkmcnt(0)" ::: "memory");                         \
    SB;                                                                        \
    __builtin_amdgcn_s_barrier();                                              \
    SB;                                                                        \
    STAGE(RB, ((T0) + 128) & 2047);                                            \
    SB;                                                                        \
    MLOAD(MKN, ((T0) + 64) & 2047);                                            \
    SB;                                                                        \
    QKMM(SN); /* QK_{r+1}, independent of softmax_r -> interleaves */          \
    /* softmax_r: mask bias fma then fixed-M exp2 */                           \
    _Pragma("unroll")                                                          \
    for (int mi = 0; mi < 2; ++mi)                                             \
      _Pragma("unroll")                                                        \
      for (int q = 0; q < 4; ++q) {                                            \
        const float4 mv = MKC[mi * 4 + q];                                     \
        SC[mi][q * 4 + 0] = fmaf(mv.x - 1.f, 144269.50408889634f, SC[mi][q * 4 + 0]); \
        SC[mi][q * 4 + 1] = fmaf(mv.y - 1.f, 144269.50408889634f, SC[mi][q * 4 + 1]); \
        SC[mi][q * 4 + 2] = fmaf(mv.z - 1.f, 144269.50408889634f, SC[mi][q * 4 + 2]); \
        SC[mi][q * 4 + 3] = fmaf(mv.w - 1.f, 144269.50408889634f, SC[mi][q * 4 + 3]); \
      }                                                                        \
    float ps0 = 0.f, ps1 = 0.f, ps2 = 0.f, ps3 = 0.f;                          \
    _Pragma("unroll")                                                          \
    for (int mi = 0; mi < 2; ++mi)                                             \
      _Pragma("unroll")                                                        \
      for (int r = 0; r < 16; r += 4) {                                        \
        SC[mi][r + 0] = myexp2(SC[mi][r + 0]); ps0 += SC[mi][r + 0];           \
        SC[mi][r + 1] = myexp2(SC[mi][r + 1]); ps1 += SC[mi][r + 1];           \
        SC[mi][r + 2] = myexp2(SC[mi][r + 2]); ps2 += SC[mi][r + 2];           \
        SC[mi][r + 3] = myexp2(SC[mi][r + 3]); ps3 += SC[mi][r + 3];           \
      }                                                                        \
    {                                                                          \
      float ps = (ps0 + ps1) + (ps2 + ps3);                                    \
      ps += __shfl_xor(ps, 32, 64);                                            \
      L += ps;                                                                 \
    }                                                                          \
    u32 dwv[2][4][2];                                                          \
    _Pragma("unroll")                                                          \
    for (int mi = 0; mi < 2; ++mi)                                             \
      _Pragma("unroll")                                                        \
      for (int q = 0; q < 4; ++q) {                                            \
        dwv[mi][q][0] = cvt_pk_bf16(SC[mi][q * 4 + 0], SC[mi][q * 4 + 1]);     \
        dwv[mi][q][1] = cvt_pk_bf16(SC[mi][q * 4 + 2], SC[mi][q * 4 + 3]);     \
      }                                                                        \
    u32 rcv[2][2][2];                                                          \
    _Pragma("unroll")                                                          \
    for (int mi = 0; mi < 2; ++mi)                                             \
      _Pragma("unroll")                                                        \
      for (int bq2 = 0; bq2 < 2; ++bq2)                                        \
        _Pragma("unroll")                                                      \
        for (int h2 = 0; h2 < 2; ++h2) {                                       \
          const u32 snd = g ? dwv[mi][bq2 * 2][h2] : dwv[mi][bq2 * 2 + 1][h2]; \
          rcv[mi][bq2][h2] = (u32)__shfl_xor((int)snd, 32, 64);                \
        }                                                                      \
    __builtin_amdgcn_s_setprio(1);                                             \
    _Pragma("unroll")                                                          \
    for (int tf = 0; tf < 4; ++tf) {                                           \
      const int m_ = tf >> 1, bq2 = tf & 1;                                    \
      const u32 a0 = dwv[m_][bq2 * 2][0],     a1 = dwv[m_][bq2 * 2][1];        \
      const u32 c0 = dwv[m_][bq2 * 2 + 1][0], c1 = dwv[m_][bq2 * 2 + 1][1];    \
      const u32 own0 = g ? c0 : a0, own1 = g ? c1 : a1;                        \
      u32x4 pw;                                                                \
      pw[0] = g ? rcv[m_][bq2][0] : own0;                                      \
      pw[1] = g ? rcv[m_][bq2][1] : own1;                                      \
      pw[2] = g ? own0 : rcv[m_][bq2][0];                                      \
      pw[3] = g ? own1 : rcv[m_][bq2][1];                                      \
      const bf16x8 pfr = __builtin_bit_cast(bf16x8, pw);                       \
      _Pragma("unroll")                                                        \
      for (int mih = 0; mih < 2; ++mih)                                        \
        ctx[mih] = __builtin_amdgcn_mfma_f32_32x32x16_bf16(vreg[mih][tf], pfr, \
                                                           ctx[mih], 0, 0, 0); \
    }                                                                          \
    __builtin_amdgcn_s_setprio(0);                                             \
  }

__global__ __launch_bounds__(128, 2) void attn_kernel(
    const float* __restrict__ mask,
    const u16* __restrict__ qt, const u16* __restrict__ kt,
    const u16* __restrict__ vt, float* __restrict__ out) {
  const int d     = blockIdx.x;   // 1024; xcd = d&7 (HW round-robin)
  const int xcd   = d & 7;
  const int b     = xcd >> 1;
  const int fthi  = xcd & 1;
  const int local = d >> 3;       // 0..127
  const int n     = local >> 4;   // slowest: co-dispatched blocks share K/V
  const int qtile = local & 15;

  const int tid  = threadIdx.x;
  const int lane = tid & 63;
  const int w    = tid >> 6;      // 0..1
  const int g    = lane >> 5;
  const int fl   = lane & 31;
  const int f    = (fthi * 16 + qtile) * 64 + w * 32 + fl;

  const u16* qtb = qt + ((size_t)b * 8 + n) * 2048 * 64;
  const u16* ktb = kt + ((size_t)b * 8 + n) * 2048 * 64;
  const u16* vb  = vt + ((size_t)b * 512 + n * 64) * 2048;
  const float* mrow = mask + ((size_t)b * 2048 + f) * 2048;

  __shared__ u16 Ks[2][64][64];  // [t][h], chunk-swizzled
  __shared__ u16 Vs[2][64][64];  // [h][t], chunk-swizzled

  bf16x8 qf[4];
#pragma unroll
  for (int kf = 0; kf < 4; ++kf)
    qf[kf] = *(const bf16x8*)(qtb + (size_t)f * 64 + kf * 16 + g * 8);

  f32x16 ctx[2];
#pragma unroll
  for (int m = 0; m < 2; ++m)
#pragma unroll
    for (int r = 0; r < 16; ++r) ctx[m][r] = 0.f;
  float L = 0.f;

  // staging geometry: wave w owns rows w*32..w*32+31 (4 gload_lds per tensor)
  // row = w*32 + 8*j + (lane>>3); row&7 == lane>>3, so one swizzle for all j
  const int srow = w * 32 + (lane >> 3);
  const int sc   = (lane & 7) ^ (lane >> 3);
  const u16* ksrc = ktb + (size_t)srow * 64 + sc * 8;   // + (T0+8j)*64
  const u16* vsrc = vb + (size_t)srow * 2048 + sc * 8;  // + j*8*2048 + T0

  bf16x8 kreg[2][4], vreg[2][4];
  float4 mkA[8], mkB[8];
  f32x16 sA[2], sB[2];

  // ---- prologue: establish invariant "at round-r top: queue =
  //      [stage(r+1) x8 (oldest), mask(r) x8]" and s_0 computed ----
  STAGE(0, 0);
  SB;
  asm volatile("s_waitcnt vmcnt(0)" ::: "memory");
  SB;
  __builtin_amdgcn_s_barrier();
  SB;
  LDK(0);
  asm volatile("s_waitcnt lgkmcnt(0)" ::: "memory");
  SB;
  __builtin_amdgcn_s_barrier();
  SB;
  STAGE(1, 64);
  SB;
  MLOAD(mkA, 0);
  SB;
  QKMM(sA);  // s_0

  for (int t0 = 0; t0 < 2048; t0 += 128) {
    ROUND(0, sA, sB, mkA, mkB, t0);        // round r   (even)
    ROUND(1, sB, sA, mkB, mkA, t0 + 64);   // round r+1 (odd)
  }

  const float Linv = 1.0f / L;
#pragma unroll
  for (int mih = 0; mih < 2; ++mih)
#pragma unroll
    for (int r = 0; r < 16; ++r) {
      const int h = mih * 32 + (r & 3) + 8 * (r >> 2) + 4 * g;
      out[((size_t)b * 512 + n * 64 + h) * 2048 + f] = ctx[mih][r] * Linv;
    }
}

extern "C" void kernel_launch(void* const* d_in, const int* in_sizes, int n_in,
                              void* d_out, int out_size, void* d_ws, size_t ws_size,
                              hipStream_t stream) {
  const float* from_t = (const float*)d_in[0];
  const float* to_t   = (const float*)d_in[1];
  const float* mask   = (const float*)d_in[2];
  const float* Wq     = (const float*)d_in[3];
  const float* bq     = (const float*)d_in[4];
  const float* Wk     = (const float*)d_in[5];
  const float* bk     = (const float*)d_in[6];
  const float* Wv     = (const float*)d_in[7];
  const float* bv     = (const float*)d_in[8];
  float* out = (float*)d_out;

  u16* qt = (u16*)d_ws;                        // [4][8][2048][64] bf16 = 8MB
  u16* kt = qt + (size_t)4 * 8 * 2048 * 64;    // 8MB
  u16* vt = kt + (size_t)4 * 8 * 2048 * 64;    // [4][512][2048] bf16 = 8MB

  proj_kernel<<<dim3(768), 256, 0, stream>>>(from_t, to_t, Wq, bq, Wk, bk,
                                             Wv, bv, qt, kt, vt);
  attn_kernel<<<dim3(1024), 128, 0, stream>>>(mask, qt, kt, vt, out);
}

// Round 9
// 130.223 us; speedup vs baseline: 1.0253x; 1.0253x over previous
//
#include <hip/hip_runtime.h>

typedef __bf16 bf16x8 __attribute__((ext_vector_type(8)));
typedef float f32x4 __attribute__((ext_vector_type(4)));
typedef float f32x16 __attribute__((ext_vector_type(16)));
typedef unsigned short u16;
typedef u16 u16x8 __attribute__((ext_vector_type(8)));
typedef unsigned int u32;
typedef u32 u32x4 __attribute__((ext_vector_type(4)));

#define DEVFN static __device__ __forceinline__

DEVFN u16 f2bf(float x) {  // RNE float->bf16 (finite inputs)
  u32 u = __builtin_bit_cast(u32, x);
  u32 r = u + 0x7FFFu + ((u >> 16) & 1u);
  return (u16)(r >> 16);
}

DEVFN float myexp2(float x) {
#if __has_builtin(__builtin_amdgcn_exp2f)
  return __builtin_amdgcn_exp2f(x);
#else
  return exp2f(x);
#endif
}

DEVFN u32 cvt_pk_bf16(float lo, float hi) {  // RNE pack: lo->[15:0], hi->[31:16]
  u32 r;
  asm("v_cvt_pk_bf16_f32 %0, %1, %2" : "=v"(r) : "v"(lo), "v"(hi));
  return r;
}

// ---------------------------------------------------------------------------
// Projection: E[b,o,f] = sum_c W[o,c] X[b,c,f] + bias[o], cast to bf16.
// mat 0 (Q): transposed [b][n][f][h], scaled by ALPHA*log2(e); 1 (K): same
// layout unscaled; 2 (V): natural [b][o][t].
// ---------------------------------------------------------------------------
__global__ __launch_bounds__(256, 2) void proj_kernel(
    const float* __restrict__ from_t, const float* __restrict__ to_t,
    const float* __restrict__ Wq, const float* __restrict__ bq,
    const float* __restrict__ Wk, const float* __restrict__ bk,
    const float* __restrict__ Wv, const float* __restrict__ bv,
    u16* __restrict__ qt, u16* __restrict__ kt, u16* __restrict__ vt) {
  const int d     = blockIdx.x;         // 768
  const int xcd   = d & 7;
  const int b     = xcd >> 1;
  const int fh    = xcd & 1;
  const int local = d >> 3;             // 0..95
  const int mat   = local >> 5;         // 0..2
  const int o0    = ((local >> 3) & 3) * 128;
  const int f0    = (fh * 8 + (local & 7)) * 128;

  const float* X    = (mat == 0) ? from_t : to_t;
  const float* W    = (mat == 0) ? Wq : (mat == 1 ? Wk : Wv);
  const float* bias = (mat == 0) ? bq : (mat == 1 ? bk : bv);
  const bool isT = (mat < 2);

  __shared__ u16 Xs[128][64];  // Xs[f][c] = X[c][f], 16B-chunk xor-swizzled
  __shared__ u16 Ws[128][64];  // Ws[o][c] = W[o][c], swizzled

  const int tid  = threadIdx.x;
  const int lane = tid & 63;
  const int w    = tid >> 6;

  f32x4 acc[4][4];
#pragma unroll
  for (int i = 0; i < 4; ++i)
#pragma unroll
    for (int j = 0; j < 4; ++j)
#pragma unroll
      for (int r = 0; r < 4; ++r) acc[i][j][r] = 0.f;

  const int arow0 = (w & 1) * 64;
  const int brow0 = (w >> 1) * 64;

  for (int c0 = 0; c0 < 512; c0 += 64) {
    __syncthreads();
#pragma unroll
    for (int i = 0; i < 4; ++i) {
      const int task = tid + 256 * i;
      const int f = task & 127, cg = task >> 7;
      const float* xp = X + ((size_t)b * 512 + c0 + cg * 8) * 2048 + f0 + f;
      float xv[8];
#pragma unroll
      for (int j = 0; j < 8; ++j) xv[j] = xp[(size_t)j * 2048];
      u32x4 pk;
#pragma unroll
      for (int j = 0; j < 4; ++j) pk[j] = cvt_pk_bf16(xv[2 * j], xv[2 * j + 1]);
      *(u32x4*)&Xs[f][(cg ^ (f & 7)) * 8] = pk;
    }
#pragma unroll
    for (int i = 0; i < 4; ++i) {
      const int task = tid + 256 * i;
      const int o = task & 127, cg = task >> 7;
      const float* wp = W + (size_t)(o0 + o) * 512 + c0 + cg * 8;
      const float4 w0 = *(const float4*)(wp);
      const float4 w1 = *(const float4*)(wp + 4);
      u32x4 pk;
      pk[0] = cvt_pk_bf16(w0.x, w0.y);
      pk[1] = cvt_pk_bf16(w0.z, w0.w);
      pk[2] = cvt_pk_bf16(w1.x, w1.y);
      pk[3] = cvt_pk_bf16(w1.z, w1.w);
      *(u32x4*)&Ws[o][(cg ^ (o & 7)) * 8] = pk;
    }
    __syncthreads();

#pragma unroll
    for (int kk = 0; kk < 2; ++kk) {
      const int cb8 = kk * 4;
      bf16x8 afr[4], bfr[4];
#pragma unroll
      for (int mi = 0; mi < 4; ++mi) {
        const int row = arow0 + mi * 16 + (lane & 15);
        const int ch  = (cb8 + (lane >> 4)) ^ (row & 7);
        afr[mi] = *(const bf16x8*)&(isT ? Xs : Ws)[row][ch * 8];
      }
#pragma unroll
      for (int ni = 0; ni < 4; ++ni) {
        const int row = brow0 + ni * 16 + (lane & 15);
        const int ch  = (cb8 + (lane >> 4)) ^ (row & 7);
        bfr[ni] = *(const bf16x8*)&(isT ? Ws : Xs)[row][ch * 8];
      }
#pragma unroll
      for (int mi = 0; mi < 4; ++mi)
#pragma unroll
        for (int ni = 0; ni < 4; ++ni)
          acc[mi][ni] = __builtin_amdgcn_mfma_f32_16x16x32_bf16(
              afr[mi], bfr[ni], acc[mi][ni], 0, 0, 0);
    }
  }

  const float qscale = 0.18033688011112042f;  // (1/8) * log2(e)
#pragma unroll
  for (int mi = 0; mi < 4; ++mi)
#pragma unroll
    for (int ni = 0; ni < 4; ++ni)
#pragma unroll
      for (int r = 0; r < 4; ++r) {
        const int rA = arow0 + mi * 16 + (lane >> 4) * 4 + r;
        const int cB = brow0 + ni * 16 + (lane & 15);
        int f, o;
        if (isT) { f = f0 + rA; o = o0 + cB; }
        else     { o = o0 + rA; f = f0 + cB; }
        float val = acc[mi][ni][r] + bias[o];
        if (mat == 0) val *= qscale;
        const u16 hv = f2bf(val);
        if (isT) {
          u16* dst = (mat == 0) ? qt : kt;
          dst[(((size_t)b * 8 + (o >> 6)) * 2048 + f) * 64 + (o & 63)] = hv;
        } else {
          vt[((size_t)b * 512 + o) * 2048 + f] = hv;
        }
      }
}

// ---------------------------------------------------------------------------
// Attention: 512 blocks x 256 thr (4 waves x 32 q-rows), KVBLK=64, LDS dbuf.
// r7 pipeline + three LDS/overlap fixes: (1) P-exchange via
// v_permlane32_swap_b32 (VALU) instead of ds_bpermute shuffles, wiring
// derived lane-exact from the verified r4 shfl version; (2) only V-reads
// drained (lgkmcnt(8)) before barrier-2 — K-reads retire under STAGE/MLOAD;
// (3) no s_setprio (it starved the partner wave's softmax VALU).
// ---------------------------------------------------------------------------
#define SB __builtin_amdgcn_sched_barrier(0)

#define STAGE(BB, T0)                                                          \
  do {                                                                         \
    __builtin_amdgcn_global_load_lds(                                          \
        (const __attribute__((address_space(1))) void*)(ksrc1 + (size_t)(T0) * 64), \
        (__attribute__((address_space(3))) void*)&Ks[BB][w * 16][0], 16, 0, 0);\
    __builtin_amdgcn_global_load_lds(                                          \
        (const __attribute__((address_space(1))) void*)(ksrc2 + (size_t)(T0) * 64), \
        (__attribute__((address_space(3))) void*)&Ks[BB][w * 16 + 8][0], 16, 0, 0); \
    __builtin_amdgcn_global_load_lds(                                          \
        (const __attribute__((address_space(1))) void*)(vsrc1 + (T0)),         \
        (__attribute__((address_space(3))) void*)&Vs[BB][w * 16][0], 16, 0, 0);\
    __builtin_amdgcn_global_load_lds(                                          \
        (const __attribute__((address_space(1))) void*)(vsrc2 + (T0)),         \
        (__attribute__((address_space(3))) void*)&Vs[BB][w * 16 + 8][0], 16, 0, 0); \
  } while (0)

#define MLOAD(MK, T0)                                                          \
  do {                                                                         \
    _Pragma("unroll")                                                          \
    for (int i_ = 0; i_ < 8; ++i_)                                             \
      MK[i_] = *(const float4*)(mrow + (T0) + (i_ >> 2) * 32 + (i_ & 3) * 8 + g * 4); \
  } while (0)

#define LDK(BUF)                                                               \
  do {                                                                         \
    _Pragma("unroll")                                                          \
    for (int kf_ = 0; kf_ < 4; ++kf_)                                          \
      _Pragma("unroll")                                                        \
      for (int mi_ = 0; mi_ < 2; ++mi_) {                                      \
        const int row_ = mi_ * 32 + fl;                                        \
        kreg[mi_][kf_] =                                                       \
            *(const bf16x8*)&Ks[BUF][row_][((kf_ * 2 + g) ^ (row_ & 7)) * 8];  \
      }                                                                        \
  } while (0)

#define LDV(BUF)                                                               \
  do {                                                                         \
    _Pragma("unroll")                                                          \
    for (int tf_ = 0; tf_ < 4; ++tf_)                                          \
      _Pragma("unroll")                                                        \
      for (int mh_ = 0; mh_ < 2; ++mh_) {                                      \
        const int row_ = mh_ * 32 + fl;                                        \
        vreg[mh_][tf_] =                                                       \
            *(const bf16x8*)&Vs[BUF][row_][((tf_ * 2 + g) ^ (row_ & 7)) * 8];  \
      }                                                                        \
  } while (0)

// QK into SN (C=0), from kreg
#define QKMM(SN)                                                               \
  do {                                                                         \
    _Pragma("unroll")                                                          \
    for (int m_ = 0; m_ < 2; ++m_)                                             \
      _Pragma("unroll")                                                        \
      for (int r_ = 0; r_ < 16; ++r_) SN[m_][r_] = 0.f;                        \
    _Pragma("unroll")                                                          \
    for (int kf_ = 0; kf_ < 4; ++kf_)                                          \
      _Pragma("unroll")                                                        \
      for (int mi_ = 0; mi_ < 2; ++mi_)                                        \
        SN[mi_] = __builtin_amdgcn_mfma_f32_32x32x16_bf16(kreg[mi_][kf_],      \
                                                          qf[kf_], SN[mi_],    \
                                                          0, 0, 0);            \
  } while (0)

// Round r: RB = r&1; SC/MKC current (consumed), SN/MKN next (produced); T0=r*64
#define ROUND(RB, SC, SN, MKC, MKN, T0)                                        \
  {                                                                            \
    asm volatile("s_waitcnt vmcnt(8)" ::: "memory");                           \
    SB;                                                                        \
    __builtin_amdgcn_s_barrier();                                              \
    SB;                                                                        \
    LDV(RB);                                                                   \
    SB;                                                                        \
    LDK(RB ^ 1);                                                               \
    SB;                                                                        \
    asm volatile("s_waitcnt lgkmcnt(8)" ::: "memory"); /* V-reads drained */   \
    SB;                                                                        \
    __builtin_amdgcn_s_barrier();                                              \
    SB;                                                                        \
    STAGE(RB, ((T0) + 128) & 2047);                                            \
    SB;                                                                        \
    MLOAD(MKN, ((T0) + 64) & 2047);                                            \
    SB;                                                                        \
    QKMM(SN); /* QK_{r+1}, independent of softmax_r -> interleaves */          \
    /* softmax_r: mask bias fma then fixed-M exp2 */                           \
    _Pragma("unroll")                                                          \
    for (int mi = 0; mi < 2; ++mi)                                             \
      _Pragma("unroll")                                                        \
      for (int q = 0; q < 4; ++q) {                                            \
        const float4 mv = MKC[mi * 4 + q];                                     \
        SC[mi][q * 4 + 0] = fmaf(mv.x - 1.f, 144269.50408889634f, SC[mi][q * 4 + 0]); \
        SC[mi][q * 4 + 1] = fmaf(mv.y - 1.f, 144269.50408889634f, SC[mi][q * 4 + 1]); \
        SC[mi][q * 4 + 2] = fmaf(mv.z - 1.f, 144269.50408889634f, SC[mi][q * 4 + 2]); \
        SC[mi][q * 4 + 3] = fmaf(mv.w - 1.f, 144269.50408889634f, SC[mi][q * 4 + 3]); \
      }                                                                        \
    float ps0 = 0.f, ps1 = 0.f, ps2 = 0.f, ps3 = 0.f;                          \
    _Pragma("unroll")                                                          \
    for (int mi = 0; mi < 2; ++mi)                                             \
      _Pragma("unroll")                                                        \
      for (int r = 0; r < 16; r += 4) {                                        \
        SC[mi][r + 0] = myexp2(SC[mi][r + 0]); ps0 += SC[mi][r + 0];           \
        SC[mi][r + 1] = myexp2(SC[mi][r + 1]); ps1 += SC[mi][r + 1];           \
        SC[mi][r + 2] = myexp2(SC[mi][r + 2]); ps2 += SC[mi][r + 2];           \
        SC[mi][r + 3] = myexp2(SC[mi][r + 3]); ps3 += SC[mi][r + 3];           \
      }                                                                        \
    {                                                                          \
      float ps = (ps0 + ps1) + (ps2 + ps3);                                    \
      ps += __shfl_xor(ps, 32, 64);                                            \
      L += ps;                                                                 \
    }                                                                          \
    /* pack P -> bf16 dwords */                                                \
    u32 dwv[2][4][2];                                                          \
    _Pragma("unroll")                                                          \
    for (int mi = 0; mi < 2; ++mi)                                             \
      _Pragma("unroll")                                                        \
      for (int q = 0; q < 4; ++q) {                                            \
        dwv[mi][q][0] = cvt_pk_bf16(SC[mi][q * 4 + 0], SC[mi][q * 4 + 1]);     \
        dwv[mi][q][1] = cvt_pk_bf16(SC[mi][q * 4 + 2], SC[mi][q * 4 + 3]);     \
      }                                                                        \
    /* PV: exchange halves via v_permlane32_swap (VALU). For A=even-q dword,  \
       C=odd-q dword: swap(A,C) -> A'={A.lo,C.lo} = pw0, C'={A.hi,C.hi-kept   \
       ... lane-exact match to the r4-verified shfl wiring} */                 \
    _Pragma("unroll")                                                          \
    for (int tf = 0; tf < 4; ++tf) {                                           \
      const int m_ = tf >> 1, bq2 = tf & 1;                                    \
      u32 A0 = dwv[m_][bq2 * 2][0], A1 = dwv[m_][bq2 * 2][1];                  \
      u32 C0 = dwv[m_][bq2 * 2 + 1][0], C1 = dwv[m_][bq2 * 2 + 1][1];          \
      asm("v_permlane32_swap_b32 %0, %1" : "+v"(A0), "+v"(C0));                \
      asm("v_permlane32_swap_b32 %0, %1" : "+v"(A1), "+v"(C1));                \
      u32x4 pw; pw[0] = A0; pw[1] = A1; pw[2] = C0; pw[3] = C1;                \
      const bf16x8 pfr = __builtin_bit_cast(bf16x8, pw);                       \
      _Pragma("unroll")                                                        \
      for (int mih = 0; mih < 2; ++mih)                                        \
        ctx[mih] = __builtin_amdgcn_mfma_f32_32x32x16_bf16(vreg[mih][tf], pfr, \
                                                           ctx[mih], 0, 0, 0); \
    }                                                                          \
  }

__global__ __launch_bounds__(256, 2) void attn_kernel(
    const float* __restrict__ mask,
    const u16* __restrict__ qt, const u16* __restrict__ kt,
    const u16* __restrict__ vt, float* __restrict__ out) {
  const int d     = blockIdx.x;   // 512; xcd = d&7 (HW round-robin)
  const int xcd   = d & 7;
  const int b     = xcd >> 1;
  const int fthi  = xcd & 1;
  const int local = d >> 3;       // 0..63
  const int n     = local & 7;
  const int ft    = fthi * 8 + (local >> 3);

  const int tid  = threadIdx.x;
  const int lane = tid & 63;
  const int w    = tid >> 6;      // 0..3
  const int g    = lane >> 5;
  const int fl   = lane & 31;
  const int f    = ft * 128 + w * 32 + fl;

  const u16* qtb = qt + ((size_t)b * 8 + n) * 2048 * 64;
  const u16* ktb = kt + ((size_t)b * 8 + n) * 2048 * 64;
  const u16* vb  = vt + ((size_t)b * 512 + n * 64) * 2048;
  const float* mrow = mask + ((size_t)b * 2048 + f) * 2048;

  __shared__ u16 Ks[2][64][64];  // [t][h], chunk-swizzled
  __shared__ u16 Vs[2][64][64];  // [h][t], chunk-swizzled

  bf16x8 qf[4];
#pragma unroll
  for (int kf = 0; kf < 4; ++kf)
    qf[kf] = *(const bf16x8*)(qtb + (size_t)f * 64 + kf * 16 + g * 8);

  f32x16 ctx[2];
#pragma unroll
  for (int m = 0; m < 2; ++m)
#pragma unroll
    for (int r = 0; r < 16; ++r) ctx[m][r] = 0.f;
  float L = 0.f;

  // staging geometry: wave w owns rows w*16..w*16+15 (2 gload_lds per tensor)
  const int sr1 = w * 16 + (lane >> 3), sr2 = sr1 + 8;
  const int sc1 = (lane & 7) ^ (sr1 & 7), sc2 = (lane & 7) ^ (sr2 & 7);
  const u16* ksrc1 = ktb + (size_t)sr1 * 64 + sc1 * 8;
  const u16* ksrc2 = ktb + (size_t)sr2 * 64 + sc2 * 8;
  const u16* vsrc1 = vb + (size_t)sr1 * 2048 + sc1 * 8;
  const u16* vsrc2 = vb + (size_t)sr2 * 2048 + sc2 * 8;

  bf16x8 kreg[2][4], vreg[2][4];
  float4 mkA[8], mkB[8];
  f32x16 sA[2], sB[2];

  // ---- prologue: establish invariant "at round-r top: queue =
  //      [stage(r+1) x4 (oldest), mask(r) x8]" and s_0 computed ----
  STAGE(0, 0);
  SB;
  asm volatile("s_waitcnt vmcnt(0)" ::: "memory");
  SB;
  __builtin_amdgcn_s_barrier();
  SB;
  LDK(0);
  asm volatile("s_waitcnt lgkmcnt(0)" ::: "memory");
  SB;
  __builtin_amdgcn_s_barrier();
  SB;
  STAGE(1, 64);
  SB;
  MLOAD(mkA, 0);
  SB;
  QKMM(sA);  // s_0

  for (int t0 = 0; t0 < 2048; t0 += 128) {
    ROUND(0, sA, sB, mkA, mkB, t0);        // round r   (even)
    ROUND(1, sB, sA, mkB, mkA, t0 + 64);   // round r+1 (odd)
  }

  const float Linv = 1.0f / L;
#pragma unroll
  for (int mih = 0; mih < 2; ++mih)
#pragma unroll
    for (int r = 0; r < 16; ++r) {
      const int h = mih * 32 + (r & 3) + 8 * (r >> 2) + 4 * g;
      out[((size_t)b * 512 + n * 64 + h) * 2048 + f] = ctx[mih][r] * Linv;
    }
}

extern "C" void kernel_launch(void* const* d_in, const int* in_sizes, int n_in,
                              void* d_out, int out_size, void* d_ws, size_t ws_size,
                              hipStream_t stream) {
  const float* from_t = (const float*)d_in[0];
  const float* to_t   = (const float*)d_in[1];
  const float* mask   = (const float*)d_in[2];
  const float* Wq     = (const float*)d_in[3];
  const float* bq     = (const float*)d_in[4];
  const float* Wk     = (const float*)d_in[5];
  const float* bk     = (const float*)d_in[6];
  const float* Wv     = (const float*)d_in[7];
  const float* bv     = (const float*)d_in[8];
  float* out = (float*)d_out;

  u16* qt = (u16*)d_ws;                        // [4][8][2048][64] bf16 = 8MB
  u16* kt = qt + (size_t)4 * 8 * 2048 * 64;    // 8MB
  u16* vt = kt + (size_t)4 * 8 * 2048 * 64;    // [4][512][2048] bf16 = 8MB

  proj_kernel<<<dim3(768), 256, 0, stream>>>(from_t, to_t, Wq, bq, Wk, bk,
                                             Wv, bv, qt, kt, vt);
  attn_kernel<<<dim3(512), 256, 0, stream>>>(mask, qt, kt, vt, out);
}

// Round 11
// 116.181 us; speedup vs baseline: 1.1492x; 1.1209x over previous
//
#include <hip/hip_runtime.h>

typedef __bf16 bf16x8 __attribute__((ext_vector_type(8)));
typedef float f32x4 __attribute__((ext_vector_type(4)));
typedef float f32x16 __attribute__((ext_vector_type(16)));
typedef unsigned short u16;
typedef u16 u16x8 __attribute__((ext_vector_type(8)));
typedef unsigned int u32;
typedef u32 u32x4 __attribute__((ext_vector_type(4)));
typedef unsigned long long u64;

#define DEVFN static __device__ __forceinline__

DEVFN u16 f2bf(float x) {  // RNE float->bf16 (finite inputs)
  u32 u = __builtin_bit_cast(u32, x);
  u32 r = u + 0x7FFFu + ((u >> 16) & 1u);
  return (u16)(r >> 16);
}

DEVFN float myexp2(float x) {
#if __has_builtin(__builtin_amdgcn_exp2f)
  return __builtin_amdgcn_exp2f(x);
#else
  return exp2f(x);
#endif
}

DEVFN u32 cvt_pk_bf16(float lo, float hi) {  // RNE pack: lo->[15:0], hi->[31:16]
  u32 r;
  asm("v_cvt_pk_bf16_f32 %0, %1, %2" : "=v"(r) : "v"(lo), "v"(hi));
  return r;
}

// ---------------------------------------------------------------------------
// Projection: E[b,o,f] = sum_c W[o,c] X[b,c,f] + bias[o], cast to bf16.
// mat 0 (Q): transposed [b][n][f][h], scaled by ALPHA*log2(e); 1 (K): same
// layout unscaled; 2 (V): natural [b][o][t].
// ---------------------------------------------------------------------------
__global__ __launch_bounds__(256, 2) void proj_kernel(
    const float* __restrict__ from_t, const float* __restrict__ to_t,
    const float* __restrict__ Wq, const float* __restrict__ bq,
    const float* __restrict__ Wk, const float* __restrict__ bk,
    const float* __restrict__ Wv, const float* __restrict__ bv,
    u16* __restrict__ qt, u16* __restrict__ kt, u16* __restrict__ vt) {
  const int d     = blockIdx.x;         // 768
  const int xcd   = d & 7;
  const int b     = xcd >> 1;
  const int fh    = xcd & 1;
  const int local = d >> 3;             // 0..95
  const int mat   = local >> 5;         // 0..2
  const int o0    = ((local >> 3) & 3) * 128;
  const int f0    = (fh * 8 + (local & 7)) * 128;

  const float* X    = (mat == 0) ? from_t : to_t;
  const float* W    = (mat == 0) ? Wq : (mat == 1 ? Wk : Wv);
  const float* bias = (mat == 0) ? bq : (mat == 1 ? bk : bv);
  const bool isT = (mat < 2);

  __shared__ u16 Xs[128][64];  // Xs[f][c] = X[c][f], 16B-chunk xor-swizzled
  __shared__ u16 Ws[128][64];  // Ws[o][c] = W[o][c], swizzled

  const int tid  = threadIdx.x;
  const int lane = tid & 63;
  const int w    = tid >> 6;

  f32x4 acc[4][4];
#pragma unroll
  for (int i = 0; i < 4; ++i)
#pragma unroll
    for (int j = 0; j < 4; ++j)
#pragma unroll
      for (int r = 0; r < 4; ++r) acc[i][j][r] = 0.f;

  const int arow0 = (w & 1) * 64;
  const int brow0 = (w >> 1) * 64;

  for (int c0 = 0; c0 < 512; c0 += 64) {
    __syncthreads();
#pragma unroll
    for (int i = 0; i < 4; ++i) {
      const int task = tid + 256 * i;
      const int f = task & 127, cg = task >> 7;
      const float* xp = X + ((size_t)b * 512 + c0 + cg * 8) * 2048 + f0 + f;
      float xv[8];
#pragma unroll
      for (int j = 0; j < 8; ++j) xv[j] = xp[(size_t)j * 2048];
      u32x4 pk;
#pragma unroll
      for (int j = 0; j < 4; ++j) pk[j] = cvt_pk_bf16(xv[2 * j], xv[2 * j + 1]);
      *(u32x4*)&Xs[f][(cg ^ (f & 7)) * 8] = pk;
    }
#pragma unroll
    for (int i = 0; i < 4; ++i) {
      const int task = tid + 256 * i;
      const int o = task & 127, cg = task >> 7;
      const float* wp = W + (size_t)(o0 + o) * 512 + c0 + cg * 8;
      const float4 w0 = *(const float4*)(wp);
      const float4 w1 = *(const float4*)(wp + 4);
      u32x4 pk;
      pk[0] = cvt_pk_bf16(w0.x, w0.y);
      pk[1] = cvt_pk_bf16(w0.z, w0.w);
      pk[2] = cvt_pk_bf16(w1.x, w1.y);
      pk[3] = cvt_pk_bf16(w1.z, w1.w);
      *(u32x4*)&Ws[o][(cg ^ (o & 7)) * 8] = pk;
    }
    __syncthreads();

#pragma unroll
    for (int kk = 0; kk < 2; ++kk) {
      const int cb8 = kk * 4;
      bf16x8 afr[4], bfr[4];
#pragma unroll
      for (int mi = 0; mi < 4; ++mi) {
        const int row = arow0 + mi * 16 + (lane & 15);
        const int ch  = (cb8 + (lane >> 4)) ^ (row & 7);
        afr[mi] = *(const bf16x8*)&(isT ? Xs : Ws)[row][ch * 8];
      }
#pragma unroll
      for (int ni = 0; ni < 4; ++ni) {
        const int row = brow0 + ni * 16 + (lane & 15);
        const int ch  = (cb8 + (lane >> 4)) ^ (row & 7);
        bfr[ni] = *(const bf16x8*)&(isT ? Ws : Xs)[row][ch * 8];
      }
#pragma unroll
      for (int mi = 0; mi < 4; ++mi)
#pragma unroll
        for (int ni = 0; ni < 4; ++ni)
          acc[mi][ni] = __builtin_amdgcn_mfma_f32_16x16x32_bf16(
              afr[mi], bfr[ni], acc[mi][ni], 0, 0, 0);
    }
  }

  const float qscale = 0.18033688011112042f;  // (1/8) * log2(e)
#pragma unroll
  for (int mi = 0; mi < 4; ++mi)
#pragma unroll
    for (int ni = 0; ni < 4; ++ni)
#pragma unroll
      for (int r = 0; r < 4; ++r) {
        const int rA = arow0 + mi * 16 + (lane >> 4) * 4 + r;
        const int cB = brow0 + ni * 16 + (lane & 15);
        int f, o;
        if (isT) { f = f0 + rA; o = o0 + cB; }
        else     { o = o0 + rA; f = f0 + cB; }
        float val = acc[mi][ni][r] + bias[o];
        if (mat == 0) val *= qscale;
        const u16 hv = f2bf(val);
        if (isT) {
          u16* dst = (mat == 0) ? qt : kt;
          dst[(((size_t)b * 8 + (o >> 6)) * 2048 + f) * 64 + (o & 63)] = hv;
        } else {
          vt[((size_t)b * 512 + o) * 2048 + f] = hv;
        }
      }
}

// ---------------------------------------------------------------------------
// Mask uniformity pre-pass: bit `tile` of fmask[b*16+ft] = (all of
// mask[b][ft*128..+128)[tile*64..+64) == 1.0f). fmask must be zeroed first.
// ---------------------------------------------------------------------------
__global__ __launch_bounds__(256, 4) void maskflag_kernel(
    const float* __restrict__ mask, u32* __restrict__ fmask) {
  const int d    = blockIdx.x;      // [b][ft][tile] = 4*16*32
  const int b    = d >> 9;
  const int ft   = (d >> 5) & 15;
  const int tile = d & 31;
  const int t    = threadIdx.x;

  const float* base =
      mask + ((size_t)b * 2048 + ft * 128) * 2048 + tile * 64;
  bool ok = true;
#pragma unroll
  for (int i = 0; i < 8; ++i) {
    const int row = (t >> 4) * 8 + i;
    const float4 v = *(const float4*)(base + (size_t)row * 2048 + (t & 15) * 4);
    ok = ok && (v.x == 1.0f) && (v.y == 1.0f) && (v.z == 1.0f) && (v.w == 1.0f);
  }
  const u64 bal = __ballot(ok);
  __shared__ u32 wok[4];
  if ((t & 63) == 0) wok[t >> 6] = (bal == ~0ull) ? 1u : 0u;
  __syncthreads();
  if (t == 0) {
    const u32 allok = wok[0] & wok[1] & wok[2] & wok[3];
    if (allok) atomicOr(&fmask[b * 16 + ft], 1u << tile);
  }
}

// ---------------------------------------------------------------------------
// Attention: 512 blocks x 256 thr (4 waves x 32 q-rows), KVBLK=64.
// 4-buffer LDS rotation -> ONE barrier + one vmcnt(0) per round (stage of
// tile r+2 goes to buf[(r+2)&3], disjoint from this round's read bufs).
// Compiler-managed lgkmcnt. Uniform-mask fast path: one scalar fmask word
// per block, per-round SALU bit test skips 8 mask loads + 32 fma (bias==0
// exactly). General-mask slow path preserved. Fixed-M softmax; r9-verified
// permlane P-exchange. Pipeline: round r does QK_{r+1} || softmax_r -> PV_r.
// ---------------------------------------------------------------------------
#define SB __builtin_amdgcn_sched_barrier(0)

#define STAGE(BB, T0)                                                          \
  do {                                                                         \
    __builtin_amdgcn_global_load_lds(                                          \
        (const __attribute__((address_space(1))) void*)(ksrc1 + (size_t)(T0) * 64), \
        (__attribute__((address_space(3))) void*)&Ks[BB][w * 16][0], 16, 0, 0);\
    __builtin_amdgcn_global_load_lds(                                          \
        (const __attribute__((address_space(1))) void*)(ksrc2 + (size_t)(T0) * 64), \
        (__attribute__((address_space(3))) void*)&Ks[BB][w * 16 + 8][0], 16, 0, 0); \
    __builtin_amdgcn_global_load_lds(                                          \
        (const __attribute__((address_space(1))) void*)(vsrc1 + (T0)),         \
        (__attribute__((address_space(3))) void*)&Vs[BB][w * 16][0], 16, 0, 0);\
    __builtin_amdgcn_global_load_lds(                                          \
        (const __attribute__((address_space(1))) void*)(vsrc2 + (T0)),         \
        (__attribute__((address_space(3))) void*)&Vs[BB][w * 16 + 8][0], 16, 0, 0); \
  } while (0)

#define LDK(BUF)                                                               \
  do {                                                                         \
    _Pragma("unroll")                                                          \
    for (int kf_ = 0; kf_ < 4; ++kf_)                                          \
      _Pragma("unroll")                                                        \
      for (int mi_ = 0; mi_ < 2; ++mi_) {                                      \
        const int row_ = mi_ * 32 + fl;                                        \
        kreg[mi_][kf_] =                                                       \
            *(const bf16x8*)&Ks[BUF][row_][((kf_ * 2 + g) ^ (row_ & 7)) * 8];  \
      }                                                                        \
  } while (0)

#define LDV(BUF)                                                               \
  do {                                                                         \
    _Pragma("unroll")                                                          \
    for (int tf_ = 0; tf_ < 4; ++tf_)                                          \
      _Pragma("unroll")                                                        \
      for (int mh_ = 0; mh_ < 2; ++mh_) {                                      \
        const int row_ = mh_ * 32 + fl;                                        \
        vreg[mh_][tf_] =                                                       \
            *(const bf16x8*)&Vs[BUF][row_][((tf_ * 2 + g) ^ (row_ & 7)) * 8];  \
      }                                                                        \
  } while (0)

// QK into SN (C=0), from kreg
#define QKMM(SN)                                                               \
  do {                                                                         \
    _Pragma("unroll")                                                          \
    for (int m_ = 0; m_ < 2; ++m_)                                             \
      _Pragma("unroll")                                                        \
      for (int r_ = 0; r_ < 16; ++r_) SN[m_][r_] = 0.f;                        \
    _Pragma("unroll")                                                          \
    for (int kf_ = 0; kf_ < 4; ++kf_)                                          \
      _Pragma("unroll")                                                        \
      for (int mi_ = 0; mi_ < 2; ++mi_)                                        \
        SN[mi_] = __builtin_amdgcn_mfma_f32_32x32x16_bf16(kreg[mi_][kf_],      \
                                                          qf[kf_], SN[mi_],    \
                                                          0, 0, 0);            \
  } while (0)

// Round r: RB = r&3; SC current scores (consumed), SN next (produced); T0=r*64
#define ROUND(RB, SC, SN, T0)                                                  \
  {                                                                            \
    asm volatile("s_waitcnt vmcnt(0)" ::: "memory");                           \
    SB;                                                                        \
    __builtin_amdgcn_s_barrier();                                              \
    SB;                                                                        \
    LDV(RB);                                                                   \
    LDK((RB + 1) & 3);                                                         \
    SB;                                                                        \
    STAGE((RB + 2) & 3, ((T0) + 128) & 2047);                                  \
    SB;                                                                        \
    QKMM(SN); /* QK_{r+1}, independent of softmax_r -> interleaves */          \
    /* softmax_r: mask bias (slow path only) then fixed-M exp2 */              \
    if (!((fmask >> ((T0) >> 6)) & 1u)) {                                      \
      float4 mk[8];                                                            \
      _Pragma("unroll")                                                        \
      for (int i_ = 0; i_ < 8; ++i_)                                           \
        mk[i_] = *(const float4*)(mrow + (T0) + (i_ >> 2) * 32 +               \
                                  (i_ & 3) * 8 + g * 4);                       \
      _Pragma("unroll")                                                        \
      for (int mi = 0; mi < 2; ++mi)                                           \
        _Pragma("unroll")                                                      \
        for (int q = 0; q < 4; ++q) {                                          \
          const float4 mv = mk[mi * 4 + q];                                    \
          SC[mi][q * 4 + 0] = fmaf(mv.x - 1.f, 144269.50408889634f, SC[mi][q * 4 + 0]); \
          SC[mi][q * 4 + 1] = fmaf(mv.y - 1.f, 144269.50408889634f, SC[mi][q * 4 + 1]); \
          SC[mi][q * 4 + 2] = fmaf(mv.z - 1.f, 144269.50408889634f, SC[mi][q * 4 + 2]); \
          SC[mi][q * 4 + 3] = fmaf(mv.w - 1.f, 144269.50408889634f, SC[mi][q * 4 + 3]); \
        }                                                                      \
    }                                                                          \
    float ps0 = 0.f, ps1 = 0.f, ps2 = 0.f, ps3 = 0.f;                          \
    _Pragma("unroll")                                                          \
    for (int mi = 0; mi < 2; ++mi)                                             \
      _Pragma("unroll")                                                        \
      for (int r = 0; r < 16; r += 4) {                                        \
        SC[mi][r + 0] = myexp2(SC[mi][r + 0]); ps0 += SC[mi][r + 0];           \
        SC[mi][r + 1] = myexp2(SC[mi][r + 1]); ps1 += SC[mi][r + 1];           \
        SC[mi][r + 2] = myexp2(SC[mi][r + 2]); ps2 += SC[mi][r + 2];           \
        SC[mi][r + 3] = myexp2(SC[mi][r + 3]); ps3 += SC[mi][r + 3];           \
      }                                                                        \
    {                                                                          \
      float ps = (ps0 + ps1) + (ps2 + ps3);                                    \
      ps += __shfl_xor(ps, 32, 64);                                            \
      L += ps;                                                                 \
    }                                                                          \
    /* pack P -> bf16 dwords; exchange halves via v_permlane32_swap (r9) */    \
    u32 dwv[2][4][2];                                                          \
    _Pragma("unroll")                                                          \
    for (int mi = 0; mi < 2; ++mi)                                             \
      _Pragma("unroll")                                                        \
      for (int q = 0; q < 4; ++q) {                                            \
        dwv[mi][q][0] = cvt_pk_bf16(SC[mi][q * 4 + 0], SC[mi][q * 4 + 1]);     \
        dwv[mi][q][1] = cvt_pk_bf16(SC[mi][q * 4 + 2], SC[mi][q * 4 + 3]);     \
      }                                                                        \
    _Pragma("unroll")                                                          \
    for (int tf = 0; tf < 4; ++tf) {                                           \
      const int m_ = tf >> 1, bq2 = tf & 1;                                    \
      u32 A0 = dwv[m_][bq2 * 2][0], A1 = dwv[m_][bq2 * 2][1];                  \
      u32 C0 = dwv[m_][bq2 * 2 + 1][0], C1 = dwv[m_][bq2 * 2 + 1][1];          \
      asm("v_permlane32_swap_b32 %0, %1" : "+v"(A0), "+v"(C0));                \
      asm("v_permlane32_swap_b32 %0, %1" : "+v"(A1), "+v"(C1));                \
      u32x4 pw; pw[0] = A0; pw[1] = A1; pw[2] = C0; pw[3] = C1;                \
      const bf16x8 pfr = __builtin_bit_cast(bf16x8, pw);                       \
      _Pragma("unroll")                                                        \
      for (int mih = 0; mih < 2; ++mih)                                        \
        ctx[mih] = __builtin_amdgcn_mfma_f32_32x32x16_bf16(vreg[mih][tf], pfr, \
                                                           ctx[mih], 0, 0, 0); \
    }                                                                          \
  }

__global__ __launch_bounds__(256, 2) void attn_kernel(
    const float* __restrict__ mask, const u32* __restrict__ fmaskbuf,
    const u16* __restrict__ qt, const u16* __restrict__ kt,
    const u16* __restrict__ vt, float* __restrict__ out) {
  const int d     = blockIdx.x;   // 512; xcd = d&7 (HW round-robin)
  const int xcd   = d & 7;
  const int b     = xcd >> 1;
  const int fthi  = xcd & 1;
  const int local = d >> 3;       // 0..63
  const int n     = local & 7;
  const int ft    = fthi * 8 + (local >> 3);

  const int tid  = threadIdx.x;
  const int lane = tid & 63;
  const int w    = tid >> 6;      // 0..3
  const int g    = lane >> 5;
  const int fl   = lane & 31;
  const int f    = ft * 128 + w * 32 + fl;

  const u16* qtb = qt + ((size_t)b * 8 + n) * 2048 * 64;
  const u16* ktb = kt + ((size_t)b * 8 + n) * 2048 * 64;
  const u16* vb  = vt + ((size_t)b * 512 + n * 64) * 2048;
  const float* mrow = mask + ((size_t)b * 2048 + f) * 2048;
  const u32 fmask = fmaskbuf ? fmaskbuf[b * 16 + ft] : 0u;

  __shared__ u16 Ks[4][64][64];  // [t][h], chunk-swizzled, 4-buffer rotation
  __shared__ u16 Vs[4][64][64];  // [h][t], chunk-swizzled

  bf16x8 qf[4];
#pragma unroll
  for (int kf = 0; kf < 4; ++kf)
    qf[kf] = *(const bf16x8*)(qtb + (size_t)f * 64 + kf * 16 + g * 8);

  f32x16 ctx[2];
#pragma unroll
  for (int m = 0; m < 2; ++m)
#pragma unroll
    for (int r = 0; r < 16; ++r) ctx[m][r] = 0.f;
  float L = 0.f;

  // staging geometry: wave w owns rows w*16..w*16+15 (2 gload_lds per tensor)
  const int sr1 = w * 16 + (lane >> 3), sr2 = sr1 + 8;
  const int sc1 = (lane & 7) ^ (sr1 & 7), sc2 = (lane & 7) ^ (sr2 & 7);
  const u16* ksrc1 = ktb + (size_t)sr1 * 64 + sc1 * 8;
  const u16* ksrc2 = ktb + (size_t)sr2 * 64 + sc2 * 8;
  const u16* vsrc1 = vb + (size_t)sr1 * 2048 + sc1 * 8;
  const u16* vsrc2 = vb + (size_t)sr2 * 2048 + sc2 * 8;

  bf16x8 kreg[2][4], vreg[2][4];
  f32x16 sA[2], sB[2];

  // ---- prologue: stage tiles 0,1; compute QK_0 into sA ----
  STAGE(0, 0);
  STAGE(1, 64);
  SB;
  asm volatile("s_waitcnt vmcnt(0)" ::: "memory");
  SB;
  __builtin_amdgcn_s_barrier();
  SB;
  LDK(0);
  QKMM(sA);  // s_0 (compiler inserts precise lgkm waits)

  for (int t0 = 0; t0 < 2048; t0 += 256) {
    ROUND(0, sA, sB, t0);
    ROUND(1, sB, sA, t0 + 64);
    ROUND(2, sA, sB, t0 + 128);
    ROUND(3, sB, sA, t0 + 192);
  }

  const float Linv = 1.0f / L;
#pragma unroll
  for (int mih = 0; mih < 2; ++mih)
#pragma unroll
    for (int r = 0; r < 16; ++r) {
      const int h = mih * 32 + (r & 3) + 8 * (r >> 2) + 4 * g;
      out[((size_t)b * 512 + n * 64 + h) * 2048 + f] = ctx[mih][r] * Linv;
    }
}

extern "C" void kernel_launch(void* const* d_in, const int* in_sizes, int n_in,
                              void* d_out, int out_size, void* d_ws, size_t ws_size,
                              hipStream_t stream) {
  const float* from_t = (const float*)d_in[0];
  const float* to_t   = (const float*)d_in[1];
  const float* mask   = (const float*)d_in[2];
  const float* Wq     = (const float*)d_in[3];
  const float* bq     = (const float*)d_in[4];
  const float* Wk     = (const float*)d_in[5];
  const float* bk     = (const float*)d_in[6];
  const float* Wv     = (const float*)d_in[7];
  const float* bv     = (const float*)d_in[8];
  float* out = (float*)d_out;

  u16* qt = (u16*)d_ws;                        // [4][8][2048][64] bf16 = 8MB
  u16* kt = qt + (size_t)4 * 8 * 2048 * 64;    // 8MB
  u16* vt = kt + (size_t)4 * 8 * 2048 * 64;    // [4][512][2048] bf16 = 8MB
  const size_t base = (size_t)24 * 1024 * 1024;
  u32* fl = (ws_size >= base + 256) ? (u32*)((char*)d_ws + base) : nullptr;

  proj_kernel<<<dim3(768), 256, 0, stream>>>(from_t, to_t, Wq, bq, Wk, bk,
                                             Wv, bv, qt, kt, vt);
  if (fl) {
    hipMemsetAsync(fl, 0, 64 * sizeof(u32), stream);
    maskflag_kernel<<<dim3(2048), 256, 0, stream>>>(mask, fl);
  }
  attn_kernel<<<dim3(512), 256, 0, stream>>>(mask, fl, qt, kt, vt, out);
}